// Round 1
// 329.947 us; speedup vs baseline: 1.1634x; 1.1634x over previous
//
#include <hip/hip_runtime.h>
#include <math.h>

#define DIM 128

typedef float f32x4v __attribute__((ext_vector_type(4)));
typedef short bf16x8 __attribute__((ext_vector_type(8)));

static __device__ __forceinline__ short f2bf(float f) {
    unsigned u = __float_as_uint(f);
    unsigned r = (u + 0x7fffu + ((u >> 16) & 1u)) >> 16;   // RNE
    return (short)r;
}
static __device__ __forceinline__ float bf2f(unsigned short s) {
    return __uint_as_float(((unsigned)s) << 16);
}

// ---------------------------------------------------------------------------
// K1: degree histogram with 4-way replicated counters to cut TCC same-line
// atomic contention. degR layout: [r*N+n] r=0..3 -> degO, r=4..7 -> degI.
__global__ __launch_bounds__(256) void k_deg(const int* __restrict__ src,
                                             const int* __restrict__ dst,
                                             int* degR, int N, int E) {
    int e = blockIdx.x * 256 + threadIdx.x;
    if (e < E) {
        int r = threadIdx.x & 3;
        atomicAdd(&degR[r * N + src[e]], 1);
        atomicAdd(&degR[(4 + r) * N + dst[e]], 1);
    }
}

// K2: per-1024-chunk sums of degI (over replicas).
__global__ __launch_bounds__(256) void k_bsum(const int* __restrict__ degR,
                                              int* __restrict__ bsum, int N) {
    __shared__ int red[4];
    int b = blockIdx.x, t = threadIdx.x;
    int idx = b * 1024 + t * 4;
    int s = 0;
    #pragma unroll
    for (int r = 4; r < 8; ++r) {
        const int* dI = degR + r * N;
        for (int j = 0; j < 4; ++j) if (idx + j < N) s += dI[idx + j];
    }
    for (int off = 32; off; off >>= 1) s += __shfl_down(s, off);
    if ((t & 63) == 0) red[t >> 6] = s;
    __syncthreads();
    if (t == 0) bsum[b] = red[0] + red[1] + red[2] + red[3];
}

// K3: per-chunk exclusive scan -> csrOff + cursor (wave 0 re-scans bsums).
__global__ __launch_bounds__(256) void k_off(const int* __restrict__ degR,
                                             const int* __restrict__ bsum,
                                             int* __restrict__ csrOff,
                                             int* __restrict__ cursor,
                                             int N, int NB) {
    __shared__ int sp[256];
    __shared__ int sbase;
    int b = blockIdx.x, t = threadIdx.x;
    if (t < 64) {
        int own = (t < NB) ? bsum[t] : 0;
        int v = own;
        for (int off = 1; off < 64; off <<= 1) {
            int u = __shfl_up(v, off);
            if (t >= off) v += u;
        }
        if (t == b) sbase = v - own;
        if (b == 0 && t == NB - 1) { csrOff[N] = v; cursor[N] = v; }
    }
    __syncthreads();
    int idx = b * 1024 + t * 4;
    int va[4] = {0, 0, 0, 0};
    #pragma unroll
    for (int r = 4; r < 8; ++r) {
        const int* dI = degR + r * N;
        for (int j = 0; j < 4; ++j) if (idx + j < N) va[j] += dI[idx + j];
    }
    int s = va[0] + va[1] + va[2] + va[3];
    sp[t] = s;
    __syncthreads();
    for (int off = 1; off < 256; off <<= 1) {
        int u = (t >= off) ? sp[t - off] : 0;
        __syncthreads();
        sp[t] += u;
        __syncthreads();
    }
    int o = sbase + sp[t] - s;
    for (int j = 0; j < 4; ++j) {
        if (idx + j < N) { csrOff[idx + j] = o; cursor[idx + j] = o; }
        o += va[j];
    }
}

// K4: merged normI + pre-scaled bf16 feat/hx + bf16 weight convert.
__global__ __launch_bounds__(256) void k_xcw(const float* __restrict__ feat,
                                             const float* __restrict__ hx,
                                             const float* __restrict__ Wi,
                                             const float* __restrict__ Wh,
                                             const int* __restrict__ degR,
                                             float* __restrict__ normIf,
                                             short* __restrict__ Wbf,
                                             short* __restrict__ fh, int N) {
    int i = blockIdx.x * 256 + threadIdx.x;
    int T1 = N * 64, T2 = N * 64 + N;
    if (i < T1) {
        int n = i >> 6, q = i & 63;
        int dO = degR[n] + degR[N + n] + degR[2 * N + n] + degR[3 * N + n];
        float ns = rsqrtf(fmaxf((float)dO, 1.0f));
        const float* spp = (q < 32) ? &feat[(size_t)n * 128 + q * 4]
                                    : &hx[(size_t)n * 128 + (q - 32) * 4];
        float4 v = *(const float4*)spp;
        short4 p;
        p.x = f2bf(v.x * ns); p.y = f2bf(v.y * ns);
        p.z = f2bf(v.z * ns); p.w = f2bf(v.w * ns);
        *(short4*)&fh[(size_t)n * 256 + q * 4] = p;   // q*4 == 128+(q-32)*4
    } else if (i < T2) {
        int n = i - T1;
        int dI = degR[4 * N + n] + degR[5 * N + n] + degR[6 * N + n] + degR[7 * N + n];
        normIf[n] = rsqrtf(fmaxf((float)dI, 1.0f));
    } else if (i < T2 + 98304) {
        int w = i - T2;
        int k = w & 127, n = (w >> 7) & 15, r = w >> 11;
        int gm = r % 6, cb = r / 6;
        const float* Wsrc = (gm < 3) ? Wi : Wh;
        int g = gm % 3;
        Wbf[w] = f2bf(Wsrc[k * 384 + g * 128 + cb * 16 + n]);
    }
}

// K5: counting-sort fill: srcSorted grouped by dst.
__global__ __launch_bounds__(256) void k_fill(const int* __restrict__ src,
                                              const int* __restrict__ dst,
                                              int* cursor, int* __restrict__ srcSorted,
                                              int E) {
    int e = blockIdx.x * 256 + threadIdx.x;
    if (e < E) {
        int pos = atomicAdd(&cursor[dst[e]], 1);
        srcSorted[pos] = src[e];
    }
}

// ---------------------------------------------------------------------------
// K6: gather-aggregate. One wave per dst node, no LDS -> high occupancy.
// Writes bf16 agg row (norm_dst folded) into d_out-as-scratch.
__global__ __launch_bounds__(256) void gather_kernel(
    const short* __restrict__ fh, const int* __restrict__ csrOff,
    const int* __restrict__ srcSorted, const float* __restrict__ normIf,
    short* __restrict__ agg, int N) {
    int wv = threadIdx.x >> 6, lane = threadIdx.x & 63;
    int d = blockIdx.x * 4 + wv;
    if (d >= N) return;
    const ushort4* fh4 = (const ushort4*)fh;
    int beg = csrOff[d], end = csrOff[d + 1];
    float4 acc = make_float4(0.f, 0.f, 0.f, 0.f);
    #pragma unroll 8
    for (int e = beg; e < end; ++e) {
        int s = srcSorted[e];                     // wave-uniform scalar load
        ushort4 v = fh4[(size_t)s * 64 + lane];   // 8B/lane, 512B/wave
        acc.x += bf2f(v.x); acc.y += bf2f(v.y);
        acc.z += bf2f(v.z); acc.w += bf2f(v.w);
    }
    float nd = normIf[d];
    short4 p;
    p.x = f2bf(acc.x * nd); p.y = f2bf(acc.y * nd);
    p.z = f2bf(acc.z * nd); p.w = f2bf(acc.w * nd);
    *(short4*)&agg[(size_t)d * 256 + lane * 4] = p;
}

// ---------------------------------------------------------------------------
// K7: dense bf16 MFMA GEMM + GRU gates.
// NEW (this round): weights staged per-cb into LDS via global_load_lds
// (width=16), double-buffered, shared by the 4 waves of the block -> L2
// weight traffic /4 and the 192 latency-exposed 16B L2 loads per wave become
// 6 async DMA issues per cb, overlapped with the previous cb's MFMAs.
// LDS layout is XOR-swizzled (16B slot ^= row&15) to make the stride-256B
// ds_read_b128 bank-conflict-free; the swizzle is applied identically on the
// global SOURCE address (global_load_lds writes linearly) and the LDS read
// address, so per-lane fragment data is bit-identical to the previous kernel.
#define GLOAD_LDS16(gp, lp)                                                   \
    __builtin_amdgcn_global_load_lds(                                         \
        (const __attribute__((address_space(1))) void*)(gp),                  \
        (__attribute__((address_space(3))) void*)(lp), 16, 0, 0)

__global__ __launch_bounds__(256, 3) void gemm_gates_kernel(
    const short* __restrict__ agg, const float* __restrict__ hx,
    const short* __restrict__ Wbf,
    const float* __restrict__ bi, const float* __restrict__ bh,
    float* __restrict__ out, int N) {
    __shared__ short wlds[2][12288];            // 2 x 24.6 KB double buffer
    const int tid = threadIdx.x;
    const int wv = tid >> 6, lane = tid & 63;
    const int l15 = lane & 15, quad = lane >> 4;
    const int rowBase = (blockIdx.x * 4 + wv) * 16;
    // N is a multiple of 16, so an active wave always has 16 valid rows.
    // Inactive waves (tail block) must still stage + hit barriers.
    const bool active = rowBase < N;

    // A-fragments preloaded to registers BEFORE any out store (agg aliases
    // out; each wave reads/writes only its own 16 rows -> no hazard).
    int arow = active ? rowBase + l15 : 0;
    const short* aPtr = agg + (size_t)arow * 256;
    bf16x8 aLo[4], aHi[4];
    #pragma unroll
    for (int kst = 0; kst < 4; ++kst) {
        aLo[kst] = *(const bf16x8*)&aPtr[kst * 32 + quad * 8];
        aHi[kst] = *(const bf16x8*)&aPtr[128 + kst * 32 + quad * 8];
    }

    // Prologue: stage cb=0 slab (each wave copies its own 6144 B chunk).
    {
        const char* gs = (const char*)Wbf;
        #pragma unroll
        for (int i = 0; i < 6; ++i) {
            int ldsByte = wv * 6144 + i * 1024 + lane * 16;
            int gByte = ldsByte ^ (((ldsByte >> 8) & 15) << 4);   // slot ^= row&15
            GLOAD_LDS16(gs + gByte, (char*)&wlds[0][0] + wv * 6144 + i * 1024);
        }
    }
    __syncthreads();   // compiler drains vmcnt(0) before s_barrier

    for (int cb = 0; cb < 8; ++cb) {
        const int buf = cb & 1;
        if (cb < 7) {   // async prefetch next slab into the other buffer
            const char* gs = (const char*)(Wbf + (size_t)(cb + 1) * 12288);
            #pragma unroll
            for (int i = 0; i < 6; ++i) {
                int ldsByte = wv * 6144 + i * 1024 + lane * 16;
                int gByte = ldsByte ^ (((ldsByte >> 8) & 15) << 4);
                GLOAD_LDS16(gs + gByte,
                            (char*)&wlds[buf ^ 1][0] + wv * 6144 + i * 1024);
            }
        }
        if (active) {
            f32x4v acc[6];
            #pragma unroll
            for (int g = 0; g < 6; ++g) acc[g] = (f32x4v){0.f, 0.f, 0.f, 0.f};
            const char* slab = (const char*)&wlds[buf][0];
            #pragma unroll
            for (int kst = 0; kst < 4; ++kst) {
                const int co = (((kst * 4 + quad) ^ l15) << 4);   // swizzled col
                #pragma unroll
                for (int g = 0; g < 3; ++g) {
                    bf16x8 bI = *(const bf16x8*)(slab + g * 4096 + l15 * 256 + co);
                    acc[g] = __builtin_amdgcn_mfma_f32_16x16x32_bf16(
                        aLo[kst], bI, acc[g], 0, 0, 0);
                    bf16x8 bH = *(const bf16x8*)(slab + (g + 3) * 4096 + l15 * 256 + co);
                    acc[g + 3] = __builtin_amdgcn_mfma_f32_16x16x32_bf16(
                        aHi[kst], bH, acc[g + 3], 0, 0, 0);
                }
            }
            int ocol = cb * 16 + l15;
            float bir = bi[ocol], biz = bi[128 + ocol], bin = bi[256 + ocol];
            float bhr = bh[ocol], bhz = bh[128 + ocol], bhn = bh[256 + ocol];
            #pragma unroll
            for (int reg = 0; reg < 4; ++reg) {
                int row = rowBase + quad * 4 + reg;
                float ir = acc[0][reg] + bir, iz = acc[1][reg] + biz, in_ = acc[2][reg] + bin;
                float hr = acc[3][reg] + bhr, hz = acc[4][reg] + bhz, hn = acc[5][reg] + bhn;
                float rg = 1.0f / (1.0f + __expf(-(ir + hr)));
                float zg = 1.0f / (1.0f + __expf(-(iz + hz)));
                float ng = tanhf(in_ + rg * hn);
                float hv = hx[(size_t)row * DIM + ocol];
                out[(size_t)row * DIM + ocol] = (1.0f - zg) * ng + zg * hv;
            }
        }
        __syncthreads();   // drains this iter's prefetch; protects buf reuse
    }
}

// ---------------------------------------------------------------------------
extern "C" void kernel_launch(void* const* d_in, const int* in_sizes, int n_in,
                              void* d_out, int out_size, void* d_ws, size_t ws_size,
                              hipStream_t stream) {
    const float* feat = (const float*)d_in[0];
    const float* hx   = (const float*)d_in[1];
    const float* Wi   = (const float*)d_in[2];
    const float* bi   = (const float*)d_in[3];
    const float* Wh   = (const float*)d_in[4];
    const float* bh   = (const float*)d_in[5];
    const int* src    = (const int*)d_in[6];
    const int* dst    = (const int*)d_in[7];
    float* out        = (float*)d_out;

    int N = in_sizes[0] / DIM;   // 50000
    int E = in_sizes[6];         // 800000
    int NB = (N + 1023) / 1024;  // 49 (<=64 required by the wave scan)

    int* wsi = (int*)d_ws;
    int* degR      = wsi;                      // 8N (4 degO + 4 degI replicas)
    int* csrOff    = wsi + 8 * N;              // N+1
    int* cursor    = wsi + 9 * N + 1;          // N+1
    int* srcSorted = wsi + 10 * N + 2;         // E
    int* bsum      = wsi + 10 * N + 2 + E;     // 64
    float* normIf  = (float*)(bsum + 64);      // N
    size_t wofs = (((size_t)(11 * N + 2 + E + 64)) * 4 + 15) & ~(size_t)15;
    short* Wbf = (short*)((char*)d_ws + wofs);         // 98304 bf16
    size_t fofs = (wofs + 98304 * 2 + 15) & ~(size_t)15;
    short* fh = (short*)((char*)d_ws + fofs);          // N*256 bf16 (~25.6MB)
    // total ws: ~31.5 MB (proven-safe budget: 51.6 MB)
    short* agg = (short*)d_out;  // bf16 agg aliased over d_out

    hipMemsetAsync(degR, 0, (size_t)(8 * N) * sizeof(int), stream);
    k_deg<<<(E + 255) / 256, 256, 0, stream>>>(src, dst, degR, N, E);
    k_bsum<<<NB, 256, 0, stream>>>(degR, bsum, N);
    k_off<<<NB, 256, 0, stream>>>(degR, bsum, csrOff, cursor, N, NB);
    k_xcw<<<(N * 65 + 98304 + 255) / 256, 256, 0, stream>>>(
        feat, hx, Wi, Wh, degR, normIf, Wbf, fh, N);
    k_fill<<<(E + 255) / 256, 256, 0, stream>>>(src, dst, cursor, srcSorted, E);

    gather_kernel<<<(N + 3) / 4, 256, 0, stream>>>(
        fh, csrOff, srcSorted, normIf, agg, N);
    gemm_gates_kernel<<<(N + 63) / 64, 256, 0, stream>>>(
        agg, hx, Wbf, bi, bh, out, N);
}